// Round 1
// baseline (13.980 us; speedup 1.0000x reference)
//
#include <hip/hip_runtime.h>

#define LN_EPS   1e-5f
#define SLOPE    0.01f

// One fused kernel: conv3x3(4->16, valid) + LN(all) + LeakyReLU + FC(1024->128)
// + LN(all) + LeakyReLU + FC(128->3). Single block, 1024 threads (16 waves).
__global__ __launch_bounds__(1024) void streamq_fused(
    const float* __restrict__ x,     // (10,10,4) HWC
    const float* __restrict__ cw,    // (16,4,3,3) OIHW
    const float* __restrict__ cb,    // (16,)
    const float* __restrict__ w1,    // (128,1024)
    const float* __restrict__ b1,    // (128,)
    const float* __restrict__ w2,    // (3,128)
    const float* __restrict__ b2,    // (3,)
    float* __restrict__ out)         // (3,)
{
    __shared__ float xs[400];                       // staged input
    __shared__ float ws[576];                       // staged conv weights
    __shared__ __align__(16) float hs[1024];        // conv out -> normalized h
    __shared__ float red[34];                       // reduction scratch + broadcast
    __shared__ float ys[128];                       // fc1 out -> normalized h2

    const int tid  = threadIdx.x;
    const int wid  = tid >> 6;
    const int lane = tid & 63;

    if (tid < 400) xs[tid] = x[tid];
    if (tid >= 400 && tid < 976) ws[tid - 400] = cw[tid - 400];
    __syncthreads();

    // ---- conv: thread tid computes output element (o, i, j), flat idx = tid
    const int o   = tid >> 6;
    const int rem = tid & 63;
    const int i   = rem >> 3;
    const int j   = rem & 7;
    float v = cb[o];
    const float* wo = &ws[o * 36];
    #pragma unroll
    for (int dh = 0; dh < 3; ++dh) {
        #pragma unroll
        for (int dw = 0; dw < 3; ++dw) {
            const float* xp = &xs[((i + dh) * 10 + (j + dw)) * 4];
            #pragma unroll
            for (int c = 0; c < 4; ++c)
                v = fmaf(xp[c], wo[c * 9 + dh * 3 + dw], v);
        }
    }

    // ---- LayerNorm #1 over all 1024 elements (raw moments)
    {
        float s = v, q = v * v;
        #pragma unroll
        for (int off = 32; off; off >>= 1) {
            s += __shfl_down(s, off);
            q += __shfl_down(q, off);
        }
        if (lane == 0) { red[wid] = s; red[16 + wid] = q; }
        __syncthreads();
        if (tid == 0) {
            float ss = 0.f, qq = 0.f;
            #pragma unroll
            for (int k = 0; k < 16; ++k) { ss += red[k]; qq += red[16 + k]; }
            float m   = ss * (1.0f / 1024.0f);
            float var = qq * (1.0f / 1024.0f) - m * m;
            red[32] = m;
            red[33] = rsqrtf(var + LN_EPS);
        }
        __syncthreads();
    }
    {
        float m = red[32], r = red[33];
        float hv = (v - m) * r;
        hv = hv >= 0.f ? hv : SLOPE * hv;
        hs[tid] = hv;
    }
    __syncthreads();

    // ---- FC1: wave `wid` computes rows wid*8 .. wid*8+7 (128 rows total)
    {
        const float4* h4 = reinterpret_cast<const float4*>(hs);
        #pragma unroll
        for (int rr = 0; rr < 8; ++rr) {
            const int row = wid * 8 + rr;
            const float4* wrow = reinterpret_cast<const float4*>(w1 + (row << 10));
            float acc = 0.f;
            #pragma unroll
            for (int u = 0; u < 4; ++u) {
                float4 wv = wrow[u * 64 + lane];
                float4 hv = h4[u * 64 + lane];
                acc = fmaf(wv.x, hv.x, acc);
                acc = fmaf(wv.y, hv.y, acc);
                acc = fmaf(wv.z, hv.z, acc);
                acc = fmaf(wv.w, hv.w, acc);
            }
            #pragma unroll
            for (int off = 32; off; off >>= 1) acc += __shfl_down(acc, off);
            if (lane == 0) ys[row] = acc + b1[row];
        }
    }
    __syncthreads();

    // ---- LayerNorm #2 over the 128 fc1 outputs
    float yv = (tid < 128) ? ys[tid] : 0.f;
    {
        float s = yv, q = yv * yv;
        #pragma unroll
        for (int off = 32; off; off >>= 1) {
            s += __shfl_down(s, off);
            q += __shfl_down(q, off);
        }
        if (lane == 0) { red[wid] = s; red[16 + wid] = q; }
        __syncthreads();
        if (tid == 0) {
            float ss = 0.f, qq = 0.f;
            #pragma unroll
            for (int k = 0; k < 16; ++k) { ss += red[k]; qq += red[16 + k]; }
            float m   = ss * (1.0f / 128.0f);
            float var = qq * (1.0f / 128.0f) - m * m;
            red[32] = m;
            red[33] = rsqrtf(var + LN_EPS);
        }
        __syncthreads();
    }
    if (tid < 128) {
        float m = red[32], r = red[33];
        float h2 = (yv - m) * r;
        h2 = h2 >= 0.f ? h2 : SLOPE * h2;
        ys[tid] = h2;
    }
    __syncthreads();

    // ---- FC2: waves 0..2 each compute one output q-value
    if (wid < 3) {
        float acc = fmaf(w2[wid * 128 + lane],      ys[lane],      0.f);
        acc       = fmaf(w2[wid * 128 + 64 + lane], ys[64 + lane], acc);
        #pragma unroll
        for (int off = 32; off; off >>= 1) acc += __shfl_down(acc, off);
        if (lane == 0) out[wid] = acc + b2[wid];
    }
}

extern "C" void kernel_launch(void* const* d_in, const int* in_sizes, int n_in,
                              void* d_out, int out_size, void* d_ws, size_t ws_size,
                              hipStream_t stream) {
    const float* x  = (const float*)d_in[0];
    const float* cw = (const float*)d_in[1];
    const float* cb = (const float*)d_in[2];
    const float* w1 = (const float*)d_in[3];
    const float* b1 = (const float*)d_in[4];
    const float* w2 = (const float*)d_in[5];
    const float* b2 = (const float*)d_in[6];
    float* out = (float*)d_out;

    streamq_fused<<<1, 1024, 0, stream>>>(x, cw, cb, w1, b1, w2, b2, out);
}

// Round 2
// 11.555 us; speedup vs baseline: 1.2098x; 1.2098x over previous
//
#include <hip/hip_runtime.h>

#define LN_EPS 1e-5f
#define SLOPE  0.01f

// K1: 128 blocks x 256 threads. Every block redundantly computes
// conv3x3(4->16) + global LayerNorm + LeakyReLU (tiny), then computes ONE
// fc1 row (dot of 1024) and writes it to ws. w1 row load hoisted to the top
// to overlap its latency with the conv/LN compute.
__global__ __launch_bounds__(256) void streamq_k1(
    const float* __restrict__ x,     // (10,10,4) HWC
    const float* __restrict__ cw,    // (16,4,3,3) OIHW
    const float* __restrict__ cb,    // (16,)
    const float* __restrict__ w1,    // (128,1024)
    const float* __restrict__ b1,    // (128,)
    float* __restrict__ ws_out)      // (128,) fc1 pre-activation
{
    __shared__ float xs[400];
    __shared__ float cws[576];
    __shared__ __align__(16) float hs[1024];
    __shared__ float red1[10];
    __shared__ float red2[4];

    const int tid  = threadIdx.x;
    const int wid  = tid >> 6;
    const int lane = tid & 63;
    const int row  = blockIdx.x;

    // Hoist the big-latency load: this block's w1 row chunk (16 B/thread).
    const float4* w4 = reinterpret_cast<const float4*>(w1 + (row << 10));
    const float4  wv = w4[tid];

    // Stage input + conv weights.
    xs[tid] = x[tid];
    if (tid < 144) xs[tid + 256] = x[tid + 256];
    cws[tid] = cw[tid];
    if (tid < 320) cws[tid + 256] = cw[tid + 256];
    if (tid < 64)  cws[tid + 512] = cw[tid + 512];
    __syncthreads();

    // Conv: each thread computes 4 output elements (flat idx tid + 256u).
    float v[4];
    float s = 0.f, q = 0.f;
    #pragma unroll
    for (int u = 0; u < 4; ++u) {
        const int f = tid + (u << 8);
        const int o = f >> 6, rem = f & 63, i = rem >> 3, j = rem & 7;
        float acc = cb[o];
        const float* wo = &cws[o * 36];
        #pragma unroll
        for (int dh = 0; dh < 3; ++dh)
            #pragma unroll
            for (int dw = 0; dw < 3; ++dw) {
                const float* xp = &xs[((i + dh) * 10 + (j + dw)) * 4];
                #pragma unroll
                for (int c = 0; c < 4; ++c)
                    acc = fmaf(xp[c], wo[c * 9 + dh * 3 + dw], acc);
            }
        v[u] = acc;
        s += acc;
        q += acc * acc;
    }

    // LayerNorm #1 stats over all 1024 (block reduce: 4 waves).
    #pragma unroll
    for (int off = 32; off; off >>= 1) {
        s += __shfl_down(s, off);
        q += __shfl_down(q, off);
    }
    if (lane == 0) { red1[wid] = s; red1[4 + wid] = q; }
    __syncthreads();
    if (tid == 0) {
        float ss = red1[0] + red1[1] + red1[2] + red1[3];
        float qq = red1[4] + red1[5] + red1[6] + red1[7];
        float m   = ss * (1.0f / 1024.0f);
        float var = qq * (1.0f / 1024.0f) - m * m;
        red1[8] = m;
        red1[9] = rsqrtf(var + LN_EPS);
    }
    __syncthreads();
    {
        const float m = red1[8], r = red1[9];
        #pragma unroll
        for (int u = 0; u < 4; ++u) {
            float hv = (v[u] - m) * r;
            hv = hv >= 0.f ? hv : SLOPE * hv;
            hs[tid + (u << 8)] = hv;
        }
    }
    __syncthreads();

    // fc1 row `row`: 256 threads x one float4 each.
    const float4* h4 = reinterpret_cast<const float4*>(hs);
    const float4  hv = h4[tid];
    float acc = wv.x * hv.x + wv.y * hv.y + wv.z * hv.z + wv.w * hv.w;
    #pragma unroll
    for (int off = 32; off; off >>= 1) acc += __shfl_down(acc, off);
    if (lane == 0) red2[wid] = acc;
    __syncthreads();
    if (tid == 0)
        ws_out[row] = red2[0] + red2[1] + red2[2] + red2[3] + b1[row];
}

// K2: 1 block x 192 threads. LayerNorm(128) + LeakyReLU + fc2 (3 outputs).
__global__ __launch_bounds__(192) void streamq_k2(
    const float* __restrict__ ys_in, // (128,) from ws
    const float* __restrict__ w2,    // (3,128)
    const float* __restrict__ b2,    // (3,)
    float* __restrict__ out)         // (3,)
{
    __shared__ float h2[128];
    __shared__ float red[8];

    const int tid  = threadIdx.x;
    const int wid  = tid >> 6;
    const int lane = tid & 63;

    const float y = (tid < 128) ? ys_in[tid] : 0.f;
    float s = y, q = y * y;
    #pragma unroll
    for (int off = 32; off; off >>= 1) {
        s += __shfl_down(s, off);
        q += __shfl_down(q, off);
    }
    if (lane == 0) { red[wid] = s; red[3 + wid] = q; }
    __syncthreads();
    if (tid == 0) {
        float ss = red[0] + red[1] + red[2];
        float qq = red[3] + red[4] + red[5];
        float m   = ss * (1.0f / 128.0f);
        float var = qq * (1.0f / 128.0f) - m * m;
        red[6] = m;
        red[7] = rsqrtf(var + LN_EPS);
    }
    __syncthreads();
    if (tid < 128) {
        float t = (y - red[6]) * red[7];
        t = t >= 0.f ? t : SLOPE * t;
        h2[tid] = t;
    }
    __syncthreads();

    // fc2: wave `wid` (0..2) computes out[wid].
    float acc = w2[wid * 128 + lane] * h2[lane]
              + w2[wid * 128 + 64 + lane] * h2[64 + lane];
    #pragma unroll
    for (int off = 32; off; off >>= 1) acc += __shfl_down(acc, off);
    if (lane == 0) out[wid] = acc + b2[wid];
}

extern "C" void kernel_launch(void* const* d_in, const int* in_sizes, int n_in,
                              void* d_out, int out_size, void* d_ws, size_t ws_size,
                              hipStream_t stream) {
    const float* x  = (const float*)d_in[0];
    const float* cw = (const float*)d_in[1];
    const float* cb = (const float*)d_in[2];
    const float* w1 = (const float*)d_in[3];
    const float* b1 = (const float*)d_in[4];
    const float* w2 = (const float*)d_in[5];
    const float* b2 = (const float*)d_in[6];
    float* out = (float*)d_out;
    float* ys  = (float*)d_ws;   // 128 floats of scratch

    streamq_k1<<<128, 256, 0, stream>>>(x, cw, cb, w1, b1, ys);
    streamq_k2<<<1, 192, 0, stream>>>(ys, w2, b2, out);
}